// Round 1
// baseline (11575.412 us; speedup 1.0000x reference)
//
#include <hip/hip_runtime.h>
#include <hip/hip_bf16.h>
#include <float.h>

#define SEQ   8192
#define INW   180
#define HID   64
#define G4    256   // 4*HID
#define OUTW  10
#define XW    318   // 10 + 64 + 180 + 64

__device__ __forceinline__ float frcp(float x)   { return __builtin_amdgcn_rcpf(x); }
__device__ __forceinline__ float sigf(float x)   { return frcp(1.0f + __expf(-x)); }
__device__ __forceinline__ float tanhf_f(float x){ return 1.0f - 2.0f * frcp(1.0f + __expf(2.0f * x)); }

// ---------------------------------------------------------------------------
// Kernel 1: pre[s][g] = x[s] @ W_ih0.T + b_ih0 + b_hh0   (parallel GEMM)
// ---------------------------------------------------------------------------
#define PRE_TS 16
__global__ __launch_bounds__(256) void k_precompute(
    const float* __restrict__ x,      // [SEQ][INW]
    const float* __restrict__ Wih0,   // [G4][INW]
    const float* __restrict__ bih0,
    const float* __restrict__ bhh0,
    float* __restrict__ pre)          // [SEQ][G4]
{
    __shared__ float xT[INW][PRE_TS];
    const int t  = threadIdx.x;
    const int s0 = blockIdx.x * PRE_TS;
    for (int i = t; i < PRE_TS * INW; i += 256) {
        int s = i / INW, k = i % INW;
        xT[k][s] = x[s0 * INW + i];   // == x[(s0+s)*INW + k]
    }
    __syncthreads();
    float acc[PRE_TS];
    const float b = bih0[t] + bhh0[t];
#pragma unroll
    for (int s = 0; s < PRE_TS; ++s) acc[s] = b;
    for (int k = 0; k < INW; ++k) {
        float w = Wih0[t * INW + k];
#pragma unroll
        for (int s = 0; s < PRE_TS; ++s) acc[s] += w * xT[k][s];
    }
#pragma unroll
    for (int s = 0; s < PRE_TS; ++s) pre[(s0 + s) * G4 + t] = acc[s];
}

// ---------------------------------------------------------------------------
// Kernel 2: the serial 2-layer LSTM recurrence. ONE block, 256 threads.
// Thread t owns gate-row t (group = t>>6 in {i,f,g,o}, unit = t&63).
// Weights live in registers. h0/h1 broadcast via LDS. c0/c1 replicated
// per-unit across the 4 gate groups (registers).
// ---------------------------------------------------------------------------
__global__ __launch_bounds__(256, 1) void k_lstm_seq(
    const float* __restrict__ pre,    // [SEQ][G4]
    const float* __restrict__ Whh0,   // [G4][HID]
    const float* __restrict__ Wih1,   // [G4][HID]
    const float* __restrict__ Whh1,   // [G4][HID]
    const float* __restrict__ bih1,
    const float* __restrict__ bhh1,
    float* __restrict__ oldh,         // [SEQ][HID]  (h0 at START of step s)
    float* __restrict__ h1h)          // [SEQ][HID]  (h1 after step s)
{
    const int t  = threadIdx.x;
    const int u  = t & 63;
    const int gi = t >> 6;

    float w0 [HID];   // W_hh0 row t
    float w1a[HID];   // W_ih1 row t
    float w1b[HID];   // W_hh1 row t
#pragma unroll
    for (int k = 0; k < HID; ++k) w0 [k] = Whh0[t * HID + k];
#pragma unroll
    for (int k = 0; k < HID; ++k) w1a[k] = Wih1[t * HID + k];
#pragma unroll
    for (int k = 0; k < HID; ++k) w1b[k] = Whh1[t * HID + k];
    const float b1 = bih1[t] + bhh1[t];

    __shared__ float h0s[HID], h1s[HID], acts0[G4], acts1[G4];
    if (t < HID) { h0s[t] = 0.0f; h1s[t] = 0.0f; oldh[t] = 0.0f; }
    float c0 = 0.0f, c1 = 0.0f;
    __syncthreads();

    float preval = pre[t];
    for (int s = 0; s < SEQ; ++s) {
        // prefetch next step's pre value (latency hides under this step)
        const int sn = (s + 1 < SEQ) ? (s + 1) : (SEQ - 1);
        float prenext = pre[sn * G4 + t];

        // ---- phase A: v0 = pre + Whh0.h0 ; v1b = b1 + Whh1.h1 (overlapped)
        float v0 = preval, v1b = b1;
#pragma unroll
        for (int k = 0; k < HID; ++k) {
            v0  += w0 [k] * h0s[k];
            v1b += w1b[k] * h1s[k];
        }
        float a0 = (gi == 2) ? tanhf_f(v0) : sigf(v0);
        acts0[t] = a0;
        __syncthreads();

        // ---- phase B: combine layer 0 (redundant across gate groups)
        {
            float ai = acts0[u], af = acts0[64 + u], ag = acts0[128 + u], ao = acts0[192 + u];
            c0 = af * c0 + ai * ag;
            float h0n = ao * tanhf_f(c0);
            if (t < HID) {
                h0s[u] = h0n;
                if (s + 1 < SEQ) oldh[(s + 1) * HID + u] = h0n;
            }
        }
        __syncthreads();

        // ---- phase C: v1 = v1b + Wih1.h0_new
        float v1 = v1b;
#pragma unroll
        for (int k = 0; k < HID; ++k) v1 += w1a[k] * h0s[k];
        float a1 = (gi == 2) ? tanhf_f(v1) : sigf(v1);
        acts1[t] = a1;
        __syncthreads();

        // ---- phase D: combine layer 1
        {
            float bi = acts1[u], bf = acts1[64 + u], bg = acts1[128 + u], bo = acts1[192 + u];
            c1 = bf * c1 + bi * bg;
            float h1n = bo * tanhf_f(c1);
            if (t >= 64 && t < 128) {
                h1s[u] = h1n;
                h1h[s * HID + u] = h1n;
            }
        }
        __syncthreads();

        preval = prenext;
    }
}

// ---------------------------------------------------------------------------
// Kernel 3a/3b: column-wise min/max of oldh  (64 cols x 8192 rows)
// ---------------------------------------------------------------------------
__global__ __launch_bounds__(256) void k_minmax1(
    const float* __restrict__ oldh, float* __restrict__ pmn, float* __restrict__ pmx)
{
    const int t = threadIdx.x, b = blockIdx.x;
    float vmn = FLT_MAX, vmx = -FLT_MAX;
    for (int i = t; i < 128 * HID; i += 256) {       // col = (t + 256j) % 64 = t & 63
        float v = oldh[b * 128 * HID + i];
        vmn = fminf(vmn, v); vmx = fmaxf(vmx, v);
    }
    __shared__ float smn[256], smx[256];
    smn[t] = vmn; smx[t] = vmx;
    __syncthreads();
    if (t < 64) {
        float m0 = fminf(fminf(smn[t], smn[t + 64]), fminf(smn[t + 128], smn[t + 192]));
        float m1 = fmaxf(fmaxf(smx[t], smx[t + 64]), fmaxf(smx[t + 128], smx[t + 192]));
        pmn[b * 64 + t] = m0; pmx[b * 64 + t] = m1;
    }
}

__global__ __launch_bounds__(256) void k_minmax2(
    const float* __restrict__ pmn, const float* __restrict__ pmx,
    float* __restrict__ mn, float* __restrict__ mx)
{
    const int t = threadIdx.x, col = t & 63, chunk = t >> 6;
    float vmn = FLT_MAX, vmx = -FLT_MAX;
    for (int r = chunk * 16; r < chunk * 16 + 16; ++r) {
        vmn = fminf(vmn, pmn[r * 64 + col]);
        vmx = fmaxf(vmx, pmx[r * 64 + col]);
    }
    __shared__ float smn[256], smx[256];
    smn[t] = vmn; smx[t] = vmx;
    __syncthreads();
    if (t < 64) {
        mn[t] = fminf(fminf(smn[t], smn[t + 64]), fminf(smn[t + 128], smn[t + 192]));
        mx[t] = fmaxf(fmaxf(smx[t], smx[t + 64]), fmaxf(smx[t + 128], smx[t + 192]));
    }
}

// ---------------------------------------------------------------------------
// Kernel 4: per-row head + HPM MLP fwd + closed-form VJP. 1 wave per row.
// X row = [out(10) | zeros(64) | input(180) | oldh_norm(64)]
// z_k = X.Wh1[k] + bh1[k]; t_k = tanh(z_k)
// F   = -(t @ Wh2.T + bh2)
// dX  = sum_k (-colsum(Wh2)_k * (1 - t_k^2)) * Wh1[k,:]
// ---------------------------------------------------------------------------
__global__ __launch_bounds__(256) void k_finalize(
    const float* __restrict__ h1h, const float* __restrict__ oldh,
    const float* __restrict__ x,
    const float* __restrict__ Wlin, const float* __restrict__ blin,
    const float* __restrict__ Wh1,  const float* __restrict__ bh1,
    const float* __restrict__ Wh2,  const float* __restrict__ bh2,
    const float* __restrict__ mn,   const float* __restrict__ mx,
    float* __restrict__ dout)
{
    float* out_o = dout;                          // [SEQ][10]
    float* out_F = dout + SEQ * OUTW;             // [SEQ][180]
    float* out_A = dout + SEQ * (OUTW + INW);     // [SEQ][318]

    const int wave = threadIdx.x >> 6, lane = threadIdx.x & 63;
    const int row  = blockIdx.x * 4 + wave;

    __shared__ float Xs[4][XW + 2];
    __shared__ float h1sh[4][HID];

    h1sh[wave][lane] = h1h[row * HID + lane];
    float mnv = mn[lane], mxv = mx[lane];
    Xs[wave][254 + lane] = (oldh[row * HID + lane] - mnv) * frcp(mxv - mnv + 1e-6f);
    Xs[wave][10 + lane]  = 0.0f;                  // hiddens block = zeros
    for (int c = lane; c < INW; c += 64) Xs[wave][74 + c] = x[row * INW + c];
    __syncthreads();

    if (lane < OUTW) {
        float o = blin[lane];
#pragma unroll
        for (int k = 0; k < HID; ++k) o += Wlin[lane * HID + k] * h1sh[wave][k];
        Xs[wave][lane] = o;
        out_o[row * OUTW + lane] = o;
    }
    __syncthreads();

    float z0 = 0.f, z1 = 0.f, s0 = 0.f, s1 = 0.f;
    for (int c = lane; c < XW; c += 64) {
        float xv = Xs[wave][c];
        z0 += xv * Wh1[c];
        z1 += xv * Wh1[XW + c];
    }
    for (int j = lane; j < INW; j += 64) {
        s0 += Wh2[j * 2 + 0];
        s1 += Wh2[j * 2 + 1];
    }
#pragma unroll
    for (int off = 32; off; off >>= 1) {
        z0 += __shfl_xor(z0, off); z1 += __shfl_xor(z1, off);
        s0 += __shfl_xor(s0, off); s1 += __shfl_xor(s1, off);
    }
    const float t0 = tanhf_f(z0 + bh1[0]);
    const float t1 = tanhf_f(z1 + bh1[1]);
    const float a0 = -s0 * (1.0f - t0 * t0);
    const float a1 = -s1 * (1.0f - t1 * t1);

    for (int c = lane; c < INW; c += 64)
        out_F[row * INW + c] = -(t0 * Wh2[c * 2 + 0] + t1 * Wh2[c * 2 + 1] + bh2[c]);
    for (int c = lane; c < XW; c += 64)
        out_A[row * XW + c] = a0 * Wh1[c] + a1 * Wh1[XW + c];
}

// ---------------------------------------------------------------------------
extern "C" void kernel_launch(void* const* d_in, const int* in_sizes, int n_in,
                              void* d_out, int out_size, void* d_ws, size_t ws_size,
                              hipStream_t stream)
{
    const float* input = (const float*)d_in[0];
    const float* Wih0  = (const float*)d_in[1];
    const float* Whh0  = (const float*)d_in[2];
    const float* bih0  = (const float*)d_in[3];
    const float* bhh0  = (const float*)d_in[4];
    const float* Wih1  = (const float*)d_in[5];
    const float* Whh1  = (const float*)d_in[6];
    const float* bih1  = (const float*)d_in[7];
    const float* bhh1  = (const float*)d_in[8];
    const float* Wlin  = (const float*)d_in[9];
    const float* blin  = (const float*)d_in[10];
    const float* Wh1   = (const float*)d_in[11];
    const float* bh1   = (const float*)d_in[12];
    const float* Wh2   = (const float*)d_in[13];
    const float* bh2   = (const float*)d_in[14];

    float* ws   = (float*)d_ws;
    float* pre  = ws;                         // SEQ*G4   = 2,097,152
    float* oldh = pre  + SEQ * G4;            // SEQ*HID  =   524,288
    float* h1h  = oldh + SEQ * HID;           // SEQ*HID  =   524,288
    float* pmn  = h1h  + SEQ * HID;           // 64*64
    float* pmx  = pmn  + 64 * 64;             // 64*64
    float* mn   = pmx  + 64 * 64;             // 64
    float* mx   = mn   + 64;                  // 64
    float* out  = (float*)d_out;

    hipLaunchKernelGGL(k_precompute, dim3(SEQ / PRE_TS), dim3(256), 0, stream,
                       input, Wih0, bih0, bhh0, pre);
    hipLaunchKernelGGL(k_lstm_seq, dim3(1), dim3(256), 0, stream,
                       pre, Whh0, Wih1, Whh1, bih1, bhh1, oldh, h1h);
    hipLaunchKernelGGL(k_minmax1, dim3(64), dim3(256), 0, stream, oldh, pmn, pmx);
    hipLaunchKernelGGL(k_minmax2, dim3(1), dim3(256), 0, stream, pmn, pmx, mn, mx);
    hipLaunchKernelGGL(k_finalize, dim3(SEQ / 4), dim3(256), 0, stream,
                       h1h, oldh, input, Wlin, blin, Wh1, bh1, Wh2, bh2, mn, mx, out);
}

// Round 2
// 9205.495 us; speedup vs baseline: 1.2574x; 1.2574x over previous
//
#include <hip/hip_runtime.h>
#include <hip/hip_bf16.h>
#include <float.h>

#define SEQ   8192
#define INW   180
#define HID   64
#define G4    256   // 4*HID
#define OUTW  10
#define XW    318   // 10 + 64 + 180 + 64

typedef float f32x4 __attribute__((ext_vector_type(4)));

__device__ __forceinline__ float frcp(float x)   { return __builtin_amdgcn_rcpf(x); }
__device__ __forceinline__ float tanhf_f(float x){ return 1.0f - 2.0f * frcp(1.0f + __expf(2.0f * x)); }
// unified gate activation: sigmoid for i/f/o, tanh (=2*sig(2x)-1) for g
__device__ __forceinline__ float gate_act(float x, bool isg) {
    float xx = isg ? 2.0f * x : x;
    float s  = frcp(1.0f + __expf(-xx));
    return isg ? 2.0f * s - 1.0f : s;
}

// ---------------------------------------------------------------------------
// Kernel 1: pre[s][t] = x[s] @ Wih0[row(t)].T + bih0[row(t)] + bhh0[row(t)]
// row(t) = (t&3)*64 + (t>>2)  — unit-major permutation used by k_lstm_seq
// ---------------------------------------------------------------------------
#define PRE_TS 16
__global__ __launch_bounds__(256) void k_precompute(
    const float* __restrict__ x,      // [SEQ][INW]
    const float* __restrict__ Wih0,   // [G4][INW]
    const float* __restrict__ bih0,
    const float* __restrict__ bhh0,
    float* __restrict__ pre)          // [SEQ][G4] (permuted rows)
{
    __shared__ float xT[INW][PRE_TS];
    const int t  = threadIdx.x;
    const int rr = (t & 3) * 64 + (t >> 2);
    const int s0 = blockIdx.x * PRE_TS;
    for (int i = t; i < PRE_TS * INW; i += 256) {
        int s = i / INW, k = i % INW;
        xT[k][s] = x[s0 * INW + i];
    }
    __syncthreads();
    float acc[PRE_TS];
    const float b = bih0[rr] + bhh0[rr];
#pragma unroll
    for (int s = 0; s < PRE_TS; ++s) acc[s] = b;
    for (int k = 0; k < INW; ++k) {
        float w = Wih0[rr * INW + k];
#pragma unroll
        for (int s = 0; s < PRE_TS; ++s) acc[s] += w * xT[k][s];
    }
#pragma unroll
    for (int s = 0; s < PRE_TS; ++s) pre[(s0 + s) * G4 + t] = acc[s];
}

// ---------------------------------------------------------------------------
// Kernel 2: serial 2-layer LSTM. ONE block, 256 threads (4 waves, 1/SIMD).
// t = 4*unit + gate. Weights for row (gate*64+unit) in f32x4 registers.
// Gate combine: 4 in-wave shuffles within the quad. h0/h1 broadcast via
// double-buffered LDS f32x4 vectors. 2 barriers per step.
// ---------------------------------------------------------------------------
__global__ __launch_bounds__(256, 1) void k_lstm_seq(
    const float* __restrict__ pre,    // [SEQ][G4] permuted
    const float* __restrict__ Whh0,   // [G4][HID]
    const float* __restrict__ Wih1,   // [G4][HID]
    const float* __restrict__ Whh1,   // [G4][HID]
    const float* __restrict__ bih1,
    const float* __restrict__ bhh1,
    float* __restrict__ oldh,         // [SEQ][HID] (h0 at START of step s)
    float* __restrict__ h1h)          // [SEQ][HID] (h1 after step s)
{
    const int t     = threadIdx.x;
    const int g     = t & 3;          // gate: 0=i 1=f 2=g 3=o
    const int u     = t >> 2;         // unit 0..63
    const int r     = g * 64 + u;     // weight/bias row
    const int lane  = t & 63;
    const int qbase = lane & ~3;      // quad base lane (within wave)
    const bool isg  = (g == 2);

    f32x4 w0q[16], w1aq[16], w1bq[16];
    {
        const f32x4* W0  = (const f32x4*)(Whh0 + r * HID);
        const f32x4* W1a = (const f32x4*)(Wih1 + r * HID);
        const f32x4* W1b = (const f32x4*)(Whh1 + r * HID);
#pragma unroll
        for (int j = 0; j < 16; ++j) { w0q[j] = W0[j]; w1aq[j] = W1a[j]; w1bq[j] = W1b[j]; }
    }
    const float b1 = bih1[r] + bhh1[r];

    __shared__ f32x4 h0q[2][16];      // h0 broadcast, double-buffered
    __shared__ f32x4 h1q[2][16];      // h1 broadcast, double-buffered
    if (t < 16) {
        f32x4 z = {0.f, 0.f, 0.f, 0.f};
        h0q[0][t] = z; h0q[1][t] = z; h1q[0][t] = z; h1q[1][t] = z;
    }
    if (t < 64) oldh[t] = 0.0f;       // oldh row 0 = initial h0 = 0

    float c0 = 0.f, c1 = 0.f;
    float preval = pre[t];            // step 0
    __syncthreads();

    for (int s = 0; s < SEQ; ++s) {
        const int p  = s & 1, pn = p ^ 1;
        const int sn = (s + 1 < SEQ) ? (s + 1) : s;
        float prenext = pre[sn * G4 + t];

        // ---- phase A: v0 = pre + Whh0.h0 ; v1pre = b1 + Whh1.h1 ----------
        float v0a = preval, v0b = 0.f, v1a = b1, v1b = 0.f;
#pragma unroll
        for (int j = 0; j < 16; ++j) {
            f32x4 h0 = h0q[p][j];
            f32x4 h1 = h1q[p][j];
            f32x4 w0 = w0q[j];
            f32x4 wb = w1bq[j];
            v0a = fmaf(w0.x, h0.x, v0a); v0b = fmaf(w0.y, h0.y, v0b);
            v0a = fmaf(w0.z, h0.z, v0a); v0b = fmaf(w0.w, h0.w, v0b);
            v1a = fmaf(wb.x, h1.x, v1a); v1b = fmaf(wb.y, h1.y, v1b);
            v1a = fmaf(wb.z, h1.z, v1a); v1b = fmaf(wb.w, h1.w, v1b);
        }
        const float v0    = v0a + v0b;
        const float v1pre = v1a + v1b;

        // gate combine within the quad (in-wave, no barrier)
        float a  = gate_act(v0, isg);
        float ai = __shfl(a, qbase + 0);
        float af = __shfl(a, qbase + 1);
        float ag = __shfl(a, qbase + 2);
        float ao = __shfl(a, qbase + 3);
        c0 = fmaf(af, c0, ai * ag);
        float h0n = ao * tanhf_f(c0);
        if (g == 0) ((float*)&h0q[pn][0])[u] = h0n;
        if (g == 1 && s + 1 < SEQ) oldh[(s + 1) * HID + u] = h0n;
        __syncthreads();

        // ---- phase C: v1 = v1pre + Wih1.h0_new ---------------------------
        float v1c = 0.f, v1d = 0.f;
#pragma unroll
        for (int j = 0; j < 16; ++j) {
            f32x4 h0 = h0q[pn][j];
            f32x4 wa = w1aq[j];
            v1c = fmaf(wa.x, h0.x, v1c); v1d = fmaf(wa.y, h0.y, v1d);
            v1c = fmaf(wa.z, h0.z, v1c); v1d = fmaf(wa.w, h0.w, v1d);
        }
        const float v1 = v1pre + v1c + v1d;

        float b  = gate_act(v1, isg);
        float bi = __shfl(b, qbase + 0);
        float bf = __shfl(b, qbase + 1);
        float bg = __shfl(b, qbase + 2);
        float bo = __shfl(b, qbase + 3);
        c1 = fmaf(bf, c1, bi * bg);
        float h1n = bo * tanhf_f(c1);
        if (g == 3) ((float*)&h1q[pn][0])[u] = h1n;
        if (g == 2) h1h[s * HID + u] = h1n;
        __syncthreads();

        preval = prenext;
    }
}

// ---------------------------------------------------------------------------
// Kernel 3a/3b: column-wise min/max of oldh (64 cols x 8192 rows)
// ---------------------------------------------------------------------------
__global__ __launch_bounds__(256) void k_minmax1(
    const float* __restrict__ oldh, float* __restrict__ pmn, float* __restrict__ pmx)
{
    const int t = threadIdx.x, b = blockIdx.x;
    float vmn = FLT_MAX, vmx = -FLT_MAX;
    for (int i = t; i < 128 * HID; i += 256) {
        float v = oldh[b * 128 * HID + i];
        vmn = fminf(vmn, v); vmx = fmaxf(vmx, v);
    }
    __shared__ float smn[256], smx[256];
    smn[t] = vmn; smx[t] = vmx;
    __syncthreads();
    if (t < 64) {
        float m0 = fminf(fminf(smn[t], smn[t + 64]), fminf(smn[t + 128], smn[t + 192]));
        float m1 = fmaxf(fmaxf(smx[t], smx[t + 64]), fmaxf(smx[t + 128], smx[t + 192]));
        pmn[b * 64 + t] = m0; pmx[b * 64 + t] = m1;
    }
}

__global__ __launch_bounds__(256) void k_minmax2(
    const float* __restrict__ pmn, const float* __restrict__ pmx,
    float* __restrict__ mn, float* __restrict__ mx)
{
    const int t = threadIdx.x, col = t & 63, chunk = t >> 6;
    float vmn = FLT_MAX, vmx = -FLT_MAX;
    for (int r = chunk * 16; r < chunk * 16 + 16; ++r) {
        vmn = fminf(vmn, pmn[r * 64 + col]);
        vmx = fmaxf(vmx, pmx[r * 64 + col]);
    }
    __shared__ float smn[256], smx[256];
    smn[t] = vmn; smx[t] = vmx;
    __syncthreads();
    if (t < 64) {
        mn[t] = fminf(fminf(smn[t], smn[t + 64]), fminf(smn[t + 128], smn[t + 192]));
        mx[t] = fmaxf(fmaxf(smx[t], smx[t + 64]), fmaxf(smx[t + 128], smx[t + 192]));
    }
}

// ---------------------------------------------------------------------------
// Kernel 4: per-row head + HPM MLP fwd + closed-form VJP. 1 wave per row.
// ---------------------------------------------------------------------------
__global__ __launch_bounds__(256) void k_finalize(
    const float* __restrict__ h1h, const float* __restrict__ oldh,
    const float* __restrict__ x,
    const float* __restrict__ Wlin, const float* __restrict__ blin,
    const float* __restrict__ Wh1,  const float* __restrict__ bh1,
    const float* __restrict__ Wh2,  const float* __restrict__ bh2,
    const float* __restrict__ mn,   const float* __restrict__ mx,
    float* __restrict__ dout)
{
    float* out_o = dout;                          // [SEQ][10]
    float* out_F = dout + SEQ * OUTW;             // [SEQ][180]
    float* out_A = dout + SEQ * (OUTW + INW);     // [SEQ][318]

    const int wave = threadIdx.x >> 6, lane = threadIdx.x & 63;
    const int row  = blockIdx.x * 4 + wave;

    __shared__ float Xs[4][XW + 2];
    __shared__ float h1sh[4][HID];

    h1sh[wave][lane] = h1h[row * HID + lane];
    float mnv = mn[lane], mxv = mx[lane];
    Xs[wave][254 + lane] = (oldh[row * HID + lane] - mnv) * frcp(mxv - mnv + 1e-6f);
    Xs[wave][10 + lane]  = 0.0f;
    for (int c = lane; c < INW; c += 64) Xs[wave][74 + c] = x[row * INW + c];
    __syncthreads();

    if (lane < OUTW) {
        float o = blin[lane];
#pragma unroll
        for (int k = 0; k < HID; ++k) o += Wlin[lane * HID + k] * h1sh[wave][k];
        Xs[wave][lane] = o;
        out_o[row * OUTW + lane] = o;
    }
    __syncthreads();

    float z0 = 0.f, z1 = 0.f, s0 = 0.f, s1 = 0.f;
    for (int c = lane; c < XW; c += 64) {
        float xv = Xs[wave][c];
        z0 += xv * Wh1[c];
        z1 += xv * Wh1[XW + c];
    }
    for (int j = lane; j < INW; j += 64) {
        s0 += Wh2[j * 2 + 0];
        s1 += Wh2[j * 2 + 1];
    }
#pragma unroll
    for (int off = 32; off; off >>= 1) {
        z0 += __shfl_xor(z0, off); z1 += __shfl_xor(z1, off);
        s0 += __shfl_xor(s0, off); s1 += __shfl_xor(s1, off);
    }
    const float t0 = tanhf_f(z0 + bh1[0]);
    const float t1 = tanhf_f(z1 + bh1[1]);
    const float a0 = -s0 * (1.0f - t0 * t0);
    const float a1 = -s1 * (1.0f - t1 * t1);

    for (int c = lane; c < INW; c += 64)
        out_F[row * INW + c] = -(t0 * Wh2[c * 2 + 0] + t1 * Wh2[c * 2 + 1] + bh2[c]);
    for (int c = lane; c < XW; c += 64)
        out_A[row * XW + c] = a0 * Wh1[c] + a1 * Wh1[XW + c];
}

// ---------------------------------------------------------------------------
extern "C" void kernel_launch(void* const* d_in, const int* in_sizes, int n_in,
                              void* d_out, int out_size, void* d_ws, size_t ws_size,
                              hipStream_t stream)
{
    const float* input = (const float*)d_in[0];
    const float* Wih0  = (const float*)d_in[1];
    const float* Whh0  = (const float*)d_in[2];
    const float* bih0  = (const float*)d_in[3];
    const float* bhh0  = (const float*)d_in[4];
    const float* Wih1  = (const float*)d_in[5];
    const float* Whh1  = (const float*)d_in[6];
    const float* bih1  = (const float*)d_in[7];
    const float* bhh1  = (const float*)d_in[8];
    const float* Wlin  = (const float*)d_in[9];
    const float* blin  = (const float*)d_in[10];
    const float* Wh1   = (const float*)d_in[11];
    const float* bh1   = (const float*)d_in[12];
    const float* Wh2   = (const float*)d_in[13];
    const float* bh2   = (const float*)d_in[14];

    float* ws   = (float*)d_ws;
    float* pre  = ws;                         // SEQ*G4
    float* oldh = pre  + SEQ * G4;            // SEQ*HID
    float* h1h  = oldh + SEQ * HID;           // SEQ*HID
    float* pmn  = h1h  + SEQ * HID;           // 64*64
    float* pmx  = pmn  + 64 * 64;             // 64*64
    float* mn   = pmx  + 64 * 64;             // 64
    float* mx   = mn   + 64;                  // 64
    float* out  = (float*)d_out;

    hipLaunchKernelGGL(k_precompute, dim3(SEQ / PRE_TS), dim3(256), 0, stream,
                       input, Wih0, bih0, bhh0, pre);
    hipLaunchKernelGGL(k_lstm_seq, dim3(1), dim3(256), 0, stream,
                       pre, Whh0, Wih1, Whh1, bih1, bhh1, oldh, h1h);
    hipLaunchKernelGGL(k_minmax1, dim3(64), dim3(256), 0, stream, oldh, pmn, pmx);
    hipLaunchKernelGGL(k_minmax2, dim3(1), dim3(256), 0, stream, pmn, pmx, mn, mx);
    hipLaunchKernelGGL(k_finalize, dim3(SEQ / 4), dim3(256), 0, stream,
                       h1h, oldh, input, Wlin, blin, Wh1, bh1, Wh2, bh2, mn, mx, out);
}

// Round 4
// 6406.604 us; speedup vs baseline: 1.8068x; 1.4369x over previous
//
#include <hip/hip_runtime.h>
#include <hip/hip_bf16.h>
#include <float.h>

#define SEQ   8192
#define INW   180
#define HID   64
#define G4    256   // 4*HID
#define OUTW  10
#define XW    318   // 10 + 64 + 180 + 64

typedef float f32x4 __attribute__((ext_vector_type(4)));

__device__ __forceinline__ float frcp(float x)   { return __builtin_amdgcn_rcpf(x); }
__device__ __forceinline__ float tanhf_f(float x){ return 1.0f - 2.0f * frcp(1.0f + __expf(2.0f * x)); }
// unified gate activation: sigmoid for i/f/o, tanh (=2*sig(2x)-1) for g
__device__ __forceinline__ float gate_act(float x, bool isg) {
    float xx = isg ? 2.0f * x : x;
    float s  = frcp(1.0f + __expf(-xx));
    return isg ? 2.0f * s - 1.0f : s;
}

// DPP quad_perm broadcast of lane (quad_base + K) to the whole quad — pure VALU
template<int CTRL>
__device__ __forceinline__ float dpp_bcast(float x) {
    return __int_as_float(__builtin_amdgcn_update_dpp(
        0, __float_as_int(x), CTRL, 0xF, 0xF, true));
}

// keep a loaded quad pinned in VGPRs (defeats rematerialization-from-global)
#define PIN4(v) asm volatile("" : "+v"((v).x), "+v"((v).y), "+v"((v).z), "+v"((v).w))

// ---------------------------------------------------------------------------
// Kernel 1: pre[s][t] = x[s] @ Wih0[row(t)].T + bih0[row(t)] + bhh0[row(t)]
// row(t) = (t&3)*64 + (t>>2)  — unit-major permutation used by k_lstm_seq
// ---------------------------------------------------------------------------
#define PRE_TS 16
__global__ __launch_bounds__(256) void k_precompute(
    const float* __restrict__ x,      // [SEQ][INW]
    const float* __restrict__ Wih0,   // [G4][INW]
    const float* __restrict__ bih0,
    const float* __restrict__ bhh0,
    float* __restrict__ pre)          // [SEQ][G4] (permuted rows)
{
    __shared__ float xT[INW][PRE_TS];
    const int t  = threadIdx.x;
    const int rr = (t & 3) * 64 + (t >> 2);
    const int s0 = blockIdx.x * PRE_TS;
    for (int i = t; i < PRE_TS * INW; i += 256) {
        int s = i / INW, k = i % INW;
        xT[k][s] = x[s0 * INW + i];
    }
    __syncthreads();
    float acc[PRE_TS];
    const float b = bih0[rr] + bhh0[rr];
#pragma unroll
    for (int s = 0; s < PRE_TS; ++s) acc[s] = b;
    for (int k = 0; k < INW; ++k) {
        float w = Wih0[rr * INW + k];
#pragma unroll
        for (int s = 0; s < PRE_TS; ++s) acc[s] += w * xT[k][s];
    }
#pragma unroll
    for (int s = 0; s < PRE_TS; ++s) pre[(s0 + s) * G4 + t] = acc[s];
}

// ---------------------------------------------------------------------------
// Kernel 2: serial 2-layer LSTM, wave-specialized layer pipeline.
// ONE block, 512 threads (8 waves, 2/SIMD). SEQ+1 barrier intervals.
//   waves 0-3 (t<256),  intervals 0..SEQ-1:  H0[s+1] = cell(x(s), H0[s], c0)
//   waves 4-7 (t>=256), intervals 1..SEQ:    Y[s-1]  = cell(H0[s], Y[s-2], c1)
// (layer1 lags one interval: reference h1(s) uses the SAME-step h0 output,
//  which is only available after the barrier that ends interval s.)
// Thread q=t&255: g=q&3 (i,f,g,o), u=q>>2. Gate combine via DPP quad bcast.
// ---------------------------------------------------------------------------
__global__ __launch_bounds__(512, 2) void k_lstm_seq(
    const float* __restrict__ pre,    // [SEQ][G4] permuted
    const float* __restrict__ Whh0,   // [G4][HID]
    const float* __restrict__ Wih1,   // [G4][HID]
    const float* __restrict__ Whh1,   // [G4][HID]
    const float* __restrict__ bih1,
    const float* __restrict__ bhh1,
    float* __restrict__ oldh,         // [SEQ][HID] (h0 at START of step s)
    float* __restrict__ h1h)          // [SEQ][HID] (h1 after step s)
{
    const int t   = threadIdx.x;
    const int q   = t & 255;
    const int g   = q & 3;            // gate: 0=i 1=f 2=g 3=o
    const int u   = q >> 2;           // unit 0..63
    const int r   = g * 64 + u;       // weight/bias row
    const bool isg = (g == 2);

    __shared__ f32x4 h0v[2][16];      // h0 broadcast, double-buffered
    __shared__ f32x4 h1v[2][16];      // h1 broadcast, double-buffered
    if (t < 16) {
        f32x4 z = {0.f, 0.f, 0.f, 0.f};
        h0v[0][t] = z; h0v[1][t] = z; h1v[0][t] = z; h1v[1][t] = z;
    }
    if (t < 64) oldh[t] = 0.0f;
    __syncthreads();

    if (t < 256) {
        // ================= layer-0 group: intervals 0..SEQ-1 =============
        f32x4 w0[16];
        {
            const f32x4* W0 = (const f32x4*)(Whh0 + r * HID);
#pragma unroll
            for (int j = 0; j < 16; ++j) w0[j] = W0[j];
#pragma unroll
            for (int j = 0; j < 16; ++j) PIN4(w0[j]);
        }
        float c0 = 0.f;
        float preval = pre[q];
        for (int s = 0; s <= SEQ; ++s) {
            if (s < SEQ) {
                const int p = s & 1, pn = p ^ 1;
                const int sn = (s + 1 < SEQ) ? (s + 1) : s;
                float prenext = pre[sn * G4 + q];

                float va = preval, vb = 0.f;
                const f32x4* H0 = (const f32x4*)&h0v[p][0];
#pragma unroll
                for (int j = 0; j < 16; ++j) {
                    f32x4 h = H0[j], w = w0[j];
                    va = fmaf(w.x, h.x, va); vb = fmaf(w.y, h.y, vb);
                    va = fmaf(w.z, h.z, va); vb = fmaf(w.w, h.w, vb);
                }
                float a  = gate_act(va + vb, isg);
                float ai = dpp_bcast<0x00>(a);
                float af = dpp_bcast<0x55>(a);
                float ag = dpp_bcast<0xAA>(a);
                float ao = dpp_bcast<0xFF>(a);
                c0 = fmaf(af, c0, ai * ag);
                float h0n = ao * tanhf_f(c0);
                if (g == 0) ((float*)&h0v[pn][0])[u] = h0n;
                if (g == 1 && s + 1 < SEQ) oldh[(s + 1) * HID + u] = h0n;
                preval = prenext;
            }
            asm volatile("s_waitcnt lgkmcnt(0)" ::: "memory");
            __builtin_amdgcn_s_barrier();
            asm volatile("" ::: "memory");
        }
    } else {
        // ================= layer-1 group: intervals 1..SEQ ===============
        f32x4 wa[16], wb[16];
        {
            const f32x4* Wa = (const f32x4*)(Wih1 + r * HID);
            const f32x4* Wb = (const f32x4*)(Whh1 + r * HID);
#pragma unroll
            for (int j = 0; j < 16; ++j) { wa[j] = Wa[j]; wb[j] = Wb[j]; }
#pragma unroll
            for (int j = 0; j < 16; ++j) { PIN4(wa[j]); PIN4(wb[j]); }
        }
        const float b1 = bih1[r] + bhh1[r];
        float c1 = 0.f;
        for (int s = 0; s <= SEQ; ++s) {
            if (s >= 1) {
                const int p = s & 1, pn = p ^ 1;

                float va = b1, vb = 0.f;
                const f32x4* H0 = (const f32x4*)&h0v[p][0];   // H0[s]
                const f32x4* H1 = (const f32x4*)&h1v[p][0];   // Y[s-2]
#pragma unroll
                for (int j = 0; j < 16; ++j) {
                    f32x4 h0 = H0[j], h1 = H1[j], A = wa[j], B = wb[j];
                    va = fmaf(A.x, h0.x, va); vb = fmaf(A.y, h0.y, vb);
                    va = fmaf(A.z, h0.z, va); vb = fmaf(A.w, h0.w, vb);
                    va = fmaf(B.x, h1.x, va); vb = fmaf(B.y, h1.y, vb);
                    va = fmaf(B.z, h1.z, va); vb = fmaf(B.w, h1.w, vb);
                }
                float a  = gate_act(va + vb, isg);
                float bi = dpp_bcast<0x00>(a);
                float bf = dpp_bcast<0x55>(a);
                float bg = dpp_bcast<0xAA>(a);
                float bo = dpp_bcast<0xFF>(a);
                c1 = fmaf(bf, c1, bi * bg);
                float h1n = bo * tanhf_f(c1);                 // Y[s-1]
                if (g == 0) ((float*)&h1v[pn][0])[u] = h1n;
                if (g == 1) h1h[(s - 1) * HID + u] = h1n;
            }
            asm volatile("s_waitcnt lgkmcnt(0)" ::: "memory");
            __builtin_amdgcn_s_barrier();
            asm volatile("" ::: "memory");
        }
    }
}

// ---------------------------------------------------------------------------
// Kernel 3a/3b: column-wise min/max of oldh (64 cols x 8192 rows)
// ---------------------------------------------------------------------------
__global__ __launch_bounds__(256) void k_minmax1(
    const float* __restrict__ oldh, float* __restrict__ pmn, float* __restrict__ pmx)
{
    const int t = threadIdx.x, b = blockIdx.x;
    float vmn = FLT_MAX, vmx = -FLT_MAX;
    for (int i = t; i < 128 * HID; i += 256) {
        float v = oldh[b * 128 * HID + i];
        vmn = fminf(vmn, v); vmx = fmaxf(vmx, v);
    }
    __shared__ float smn[256], smx[256];
    smn[t] = vmn; smx[t] = vmx;
    __syncthreads();
    if (t < 64) {
        float m0 = fminf(fminf(smn[t], smn[t + 64]), fminf(smn[t + 128], smn[t + 192]));
        float m1 = fmaxf(fmaxf(smx[t], smx[t + 64]), fmaxf(smx[t + 128], smx[t + 192]));
        pmn[b * 64 + t] = m0; pmx[b * 64 + t] = m1;
    }
}

__global__ __launch_bounds__(256) void k_minmax2(
    const float* __restrict__ pmn, const float* __restrict__ pmx,
    float* __restrict__ mn, float* __restrict__ mx)
{
    const int t = threadIdx.x, col = t & 63, chunk = t >> 6;
    float vmn = FLT_MAX, vmx = -FLT_MAX;
    for (int r = chunk * 16; r < chunk * 16 + 16; ++r) {
        vmn = fminf(vmn, pmn[r * 64 + col]);
        vmx = fmaxf(vmx, pmx[r * 64 + col]);
    }
    __shared__ float smn[256], smx[256];
    smn[t] = vmn; smx[t] = vmx;
    __syncthreads();
    if (t < 64) {
        mn[t] = fminf(fminf(smn[t], smn[t + 64]), fminf(smn[t + 128], smn[t + 192]));
        mx[t] = fmaxf(fmaxf(smx[t], smx[t + 64]), fmaxf(smx[t + 128], smx[t + 192]));
    }
}

// ---------------------------------------------------------------------------
// Kernel 4: per-row head + HPM MLP fwd + closed-form VJP. 1 wave per row.
// ---------------------------------------------------------------------------
__global__ __launch_bounds__(256) void k_finalize(
    const float* __restrict__ h1h, const float* __restrict__ oldh,
    const float* __restrict__ x,
    const float* __restrict__ Wlin, const float* __restrict__ blin,
    const float* __restrict__ Wh1,  const float* __restrict__ bh1,
    const float* __restrict__ Wh2,  const float* __restrict__ bh2,
    const float* __restrict__ mn,   const float* __restrict__ mx,
    float* __restrict__ dout)
{
    float* out_o = dout;                          // [SEQ][10]
    float* out_F = dout + SEQ * OUTW;             // [SEQ][180]
    float* out_A = dout + SEQ * (OUTW + INW);     // [SEQ][318]

    const int wave = threadIdx.x >> 6, lane = threadIdx.x & 63;
    const int row  = blockIdx.x * 4 + wave;

    __shared__ float Xs[4][XW + 2];
    __shared__ float h1sh[4][HID];

    h1sh[wave][lane] = h1h[row * HID + lane];
    float mnv = mn[lane], mxv = mx[lane];
    Xs[wave][254 + lane] = (oldh[row * HID + lane] - mnv) * frcp(mxv - mnv + 1e-6f);
    Xs[wave][10 + lane]  = 0.0f;
    for (int c = lane; c < INW; c += 64) Xs[wave][74 + c] = x[row * INW + c];
    __syncthreads();

    if (lane < OUTW) {
        float o = blin[lane];
#pragma unroll
        for (int k = 0; k < HID; ++k) o += Wlin[lane * HID + k] * h1sh[wave][k];
        Xs[wave][lane] = o;
        out_o[row * OUTW + lane] = o;
    }
    __syncthreads();

    float z0 = 0.f, z1 = 0.f, s0 = 0.f, s1 = 0.f;
    for (int c = lane; c < XW; c += 64) {
        float xv = Xs[wave][c];
        z0 += xv * Wh1[c];
        z1 += xv * Wh1[XW + c];
    }
    for (int j = lane; j < INW; j += 64) {
        s0 += Wh2[j * 2 + 0];
        s1 += Wh2[j * 2 + 1];
    }
#pragma unroll
    for (int off = 32; off; off >>= 1) {
        z0 += __shfl_xor(z0, off); z1 += __shfl_xor(z1, off);
        s0 += __shfl_xor(s0, off); s1 += __shfl_xor(s1, off);
    }
    const float t0 = tanhf_f(z0 + bh1[0]);
    const float t1 = tanhf_f(z1 + bh1[1]);
    const float a0 = -s0 * (1.0f - t0 * t0);
    const float a1 = -s1 * (1.0f - t1 * t1);

    for (int c = lane; c < INW; c += 64)
        out_F[row * INW + c] = -(t0 * Wh2[c * 2 + 0] + t1 * Wh2[c * 2 + 1] + bh2[c]);
    for (int c = lane; c < XW; c += 64)
        out_A[row * XW + c] = a0 * Wh1[c] + a1 * Wh1[XW + c];
}

// ---------------------------------------------------------------------------
extern "C" void kernel_launch(void* const* d_in, const int* in_sizes, int n_in,
                              void* d_out, int out_size, void* d_ws, size_t ws_size,
                              hipStream_t stream)
{
    const float* input = (const float*)d_in[0];
    const float* Wih0  = (const float*)d_in[1];
    const float* Whh0  = (const float*)d_in[2];
    const float* bih0  = (const float*)d_in[3];
    const float* bhh0  = (const float*)d_in[4];
    const float* Wih1  = (const float*)d_in[5];
    const float* Whh1  = (const float*)d_in[6];
    const float* bih1  = (const float*)d_in[7];
    const float* bhh1  = (const float*)d_in[8];
    const float* Wlin  = (const float*)d_in[9];
    const float* blin  = (const float*)d_in[10];
    const float* Wh1   = (const float*)d_in[11];
    const float* bh1   = (const float*)d_in[12];
    const float* Wh2   = (const float*)d_in[13];
    const float* bh2   = (const float*)d_in[14];

    float* ws   = (float*)d_ws;
    float* pre  = ws;                         // SEQ*G4
    float* oldh = pre  + SEQ * G4;            // SEQ*HID
    float* h1h  = oldh + SEQ * HID;           // SEQ*HID
    float* pmn  = h1h  + SEQ * HID;           // 64*64
    float* pmx  = pmn  + 64 * 64;             // 64*64
    float* mn   = pmx  + 64 * 64;             // 64
    float* mx   = mn   + 64;                  // 64
    float* out  = (float*)d_out;

    hipLaunchKernelGGL(k_precompute, dim3(SEQ / PRE_TS), dim3(256), 0, stream,
                       input, Wih0, bih0, bhh0, pre);
    hipLaunchKernelGGL(k_lstm_seq, dim3(1), dim3(512), 0, stream,
                       pre, Whh0, Wih1, Whh1, bih1, bhh1, oldh, h1h);
    hipLaunchKernelGGL(k_minmax1, dim3(64), dim3(256), 0, stream, oldh, pmn, pmx);
    hipLaunchKernelGGL(k_minmax2, dim3(1), dim3(256), 0, stream, pmn, pmx, mn, mx);
    hipLaunchKernelGGL(k_finalize, dim3(SEQ / 4), dim3(256), 0, stream,
                       h1h, oldh, input, Wlin, blin, Wh1, bh1, Wh2, bh2, mn, mx, out);
}